// Round 1
// baseline (1221.015 us; speedup 1.0000x reference)
//
#include <hip/hip_runtime.h>
#include <hip/hip_bf16.h>

#define MM 8192
#define NN 11008
#define KK 4096
#define PKW 2048   // packed int32 words per output row

#define BM 128
#define BN 128
#define BK 64

typedef __attribute__((ext_vector_type(4))) float f32x4;
typedef __attribute__((ext_vector_type(4))) int   i32x4;
typedef __attribute__((ext_vector_type(8))) short s16x8;
typedef __attribute__((ext_vector_type(4))) short s16x4;

typedef __attribute__((address_space(3))) unsigned char        lds_u8;
typedef const __attribute__((address_space(1))) unsigned char  glb_u8;

static __device__ __forceinline__ unsigned short f2bf(float f) {
  union { float f; unsigned int u; } v; v.f = f;
  unsigned int u = v.u;
  u += 0x7fffu + ((u >> 16) & 1u);   // RNE
  return (unsigned short)(u >> 16);
}

// ---------------- preprocessing ----------------

__global__ void int4lin_cvt_x(const float* __restrict__ X, unsigned short* __restrict__ O) {
  const int n8 = (MM * KK) / 8;
  int i = blockIdx.x * blockDim.x + threadIdx.x;
  const int stride = gridDim.x * blockDim.x;
  for (; i < n8; i += stride) {
    const f32x4* p = (const f32x4*)(X + (size_t)i * 8);
    f32x4 a = p[0];
    f32x4 b = p[1];
    s16x8 o;
    o[0] = (short)f2bf(a[0]); o[1] = (short)f2bf(a[1]);
    o[2] = (short)f2bf(a[2]); o[3] = (short)f2bf(a[3]);
    o[4] = (short)f2bf(b[0]); o[5] = (short)f2bf(b[1]);
    o[6] = (short)f2bf(b[2]); o[7] = (short)f2bf(b[3]);
    *(s16x8*)(O + (size_t)i * 8) = o;
  }
}

// packed (N, PKW) int32, each low byte = two nibbles (low first) -> q in [-7,8] as exact bf16
__global__ void int4lin_deq_w(const int* __restrict__ P, unsigned short* __restrict__ O) {
  const int n4 = (NN * PKW) / 4;
  int i = blockIdx.x * blockDim.x + threadIdx.x;
  const int stride = gridDim.x * blockDim.x;
  for (; i < n4; i += stride) {
    i32x4 v = *(const i32x4*)(P + (size_t)i * 4);
    s16x8 o;
#pragma unroll
    for (int j = 0; j < 4; ++j) {
      int b = v[j];
      o[2 * j]     = (short)f2bf((float)((b & 15) - 7));
      o[2 * j + 1] = (short)f2bf((float)(((b >> 4) & 15) - 7));
    }
    *(s16x8*)(O + (size_t)i * 8) = o;
  }
}

// ---------------- GEMM, predequantized bf16 path (m97 structure) ----------------

__global__ __launch_bounds__(256) void int4lin_gemm_pre(
    const unsigned short* __restrict__ A,   // M x K bf16
    const unsigned short* __restrict__ B,   // N x K bf16 (q values, unscaled)
    const float* __restrict__ scale,
    const float* __restrict__ bias,
    float* __restrict__ C)
{
  __shared__ unsigned short As[BM * BK];
  __shared__ unsigned short Bs[BN * BK];

  const int tid  = threadIdx.x;
  const int lane = tid & 63;
  const int wave = tid >> 6;
  const int m0 = blockIdx.y * BM;
  const int n0 = blockIdx.x * BN;
  const int wr = (wave >> 1) * 64;
  const int wc = (wave & 1) * 64;

  f32x4 acc[4][4] = {};

  const int seg0 = wave * 4;
  for (int kt = 0; kt < KK; kt += BK) {
#pragma unroll
    for (int i = 0; i < 4; ++i) {
      const int seg  = seg0 + i;              // 16 segments of 1 KiB
      const int flat = seg * 512 + lane * 8;  // element index within tile
      const int row  = flat >> 6;
      const int col  = flat & 63;
      __builtin_amdgcn_global_load_lds(
          (glb_u8*)(A + (size_t)(m0 + row) * KK + kt + col),
          (lds_u8*)(As + seg * 512), 16, 0, 0);
      __builtin_amdgcn_global_load_lds(
          (glb_u8*)(B + (size_t)(n0 + row) * KK + kt + col),
          (lds_u8*)(Bs + seg * 512), 16, 0, 0);
    }
    __syncthreads();
#pragma unroll
    for (int kk = 0; kk < 2; ++kk) {
      const int rsel = lane & 15;
      const int ksel = ((lane >> 4) << 3) + kk * 32;
      s16x8 af[4], bfr[4];
#pragma unroll
      for (int m = 0; m < 4; ++m)
        af[m] = *(const s16x8*)(As + (wr + m * 16 + rsel) * BK + ksel);
#pragma unroll
      for (int n = 0; n < 4; ++n)
        bfr[n] = *(const s16x8*)(Bs + (wc + n * 16 + rsel) * BK + ksel);
#pragma unroll
      for (int m = 0; m < 4; ++m)
#pragma unroll
        for (int n = 0; n < 4; ++n)
          acc[m][n] = __builtin_amdgcn_mfma_f32_16x16x32_bf16(af[m], bfr[n], acc[m][n], 0, 0, 0);
    }
    __syncthreads();
  }

  // epilogue: y = acc * scale[col] + bias[col]; C/D map col=lane&15, row=(lane>>4)*4+r
  const int crow = wr + ((lane >> 4) << 2);
  const int ccol = wc + (lane & 15);
#pragma unroll
  for (int n = 0; n < 4; ++n) {
    const int gc = n0 + ccol + n * 16;
    const float sc = scale[gc];
    const float bi = bias[gc];
#pragma unroll
    for (int m = 0; m < 4; ++m) {
      float* cp = C + (size_t)(m0 + crow + m * 16) * NN + gc;
#pragma unroll
      for (int r = 0; r < 4; ++r)
        cp[(size_t)r * NN] = acc[m][n][r] * sc + bi;
    }
  }
}

// ---------------- GEMM, inline-conversion fallback (no workspace needed) ----------------

__global__ __launch_bounds__(256) void int4lin_gemm_inline(
    const float* __restrict__ X,
    const int* __restrict__ P,
    const float* __restrict__ scale,
    const float* __restrict__ bias,
    float* __restrict__ C)
{
  __shared__ unsigned short As[BM * BK];
  __shared__ unsigned short Bs[BN * BK];

  const int tid  = threadIdx.x;
  const int lane = tid & 63;
  const int wave = tid >> 6;
  const int m0 = blockIdx.y * BM;
  const int n0 = blockIdx.x * BN;
  const int wr = (wave >> 1) * 64;
  const int wc = (wave & 1) * 64;

  f32x4 acc[4][4] = {};

  for (int kt = 0; kt < KK; kt += BK) {
    // stage A: 128x64 fp32 -> bf16, 2048 float4 chunks, 8 per thread
#pragma unroll
    for (int i = 0; i < 8; ++i) {
      const int idx = i * 256 + tid;
      const int row = idx >> 4;
      const int c   = (idx & 15) << 2;
      f32x4 v = *(const f32x4*)(X + (size_t)(m0 + row) * KK + kt + c);
      s16x4 o;
      o[0] = (short)f2bf(v[0]); o[1] = (short)f2bf(v[1]);
      o[2] = (short)f2bf(v[2]); o[3] = (short)f2bf(v[3]);
      *(s16x4*)(As + row * BK + c) = o;
    }
    // stage B: 128 rows x 32 int32 -> 64 bf16, 1024 int4 chunks, 4 per thread
#pragma unroll
    for (int i = 0; i < 4; ++i) {
      const int idx = i * 256 + tid;
      const int row = idx >> 3;
      const int c   = (idx & 7) << 3;   // bf16 col, multiple of 8
      i32x4 v = *(const i32x4*)(P + (size_t)(n0 + row) * PKW + ((kt + c) >> 1));
      s16x8 o;
#pragma unroll
      for (int j = 0; j < 4; ++j) {
        const int b = v[j];
        o[2 * j]     = (short)f2bf((float)((b & 15) - 7));
        o[2 * j + 1] = (short)f2bf((float)(((b >> 4) & 15) - 7));
      }
      *(s16x8*)(Bs + row * BK + c) = o;
    }
    __syncthreads();
#pragma unroll
    for (int kk = 0; kk < 2; ++kk) {
      const int rsel = lane & 15;
      const int ksel = ((lane >> 4) << 3) + kk * 32;
      s16x8 af[4], bfr[4];
#pragma unroll
      for (int m = 0; m < 4; ++m)
        af[m] = *(const s16x8*)(As + (wr + m * 16 + rsel) * BK + ksel);
#pragma unroll
      for (int n = 0; n < 4; ++n)
        bfr[n] = *(const s16x8*)(Bs + (wc + n * 16 + rsel) * BK + ksel);
#pragma unroll
      for (int m = 0; m < 4; ++m)
#pragma unroll
        for (int n = 0; n < 4; ++n)
          acc[m][n] = __builtin_amdgcn_mfma_f32_16x16x32_bf16(af[m], bfr[n], acc[m][n], 0, 0, 0);
    }
    __syncthreads();
  }

  const int crow = wr + ((lane >> 4) << 2);
  const int ccol = wc + (lane & 15);
#pragma unroll
  for (int n = 0; n < 4; ++n) {
    const int gc = n0 + ccol + n * 16;
    const float sc = scale[gc];
    const float bi = bias[gc];
#pragma unroll
    for (int m = 0; m < 4; ++m) {
      float* cp = C + (size_t)(m0 + crow + m * 16) * NN + gc;
#pragma unroll
      for (int r = 0; r < 4; ++r)
        cp[(size_t)r * NN] = acc[m][n][r] * sc + bi;
    }
  }
}

// ---------------- launch ----------------

extern "C" void kernel_launch(void* const* d_in, const int* in_sizes, int n_in,
                              void* d_out, int out_size, void* d_ws, size_t ws_size,
                              hipStream_t stream) {
  const float* x      = (const float*)d_in[0];
  const int*   packed = (const int*)d_in[1];
  const float* scale  = (const float*)d_in[2];
  const float* bias   = (const float*)d_in[3];
  float* y = (float*)d_out;

  const size_t nA = (size_t)MM * KK * sizeof(unsigned short);   // 64 MiB
  const size_t nB = (size_t)NN * KK * sizeof(unsigned short);   // ~86 MiB
  dim3 grid(NN / BN, MM / BM);   // 86 x 64

  if (ws_size >= nA + nB) {
    unsigned short* xb = (unsigned short*)d_ws;
    unsigned short* wb = (unsigned short*)((char*)d_ws + nA);
    int4lin_cvt_x<<<2048, 256, 0, stream>>>(x, xb);
    int4lin_deq_w<<<2048, 256, 0, stream>>>(packed, wb);
    int4lin_gemm_pre<<<grid, 256, 0, stream>>>(xb, wb, scale, bias, y);
  } else {
    int4lin_gemm_inline<<<grid, 256, 0, stream>>>(x, packed, scale, bias, y);
  }
}

// Round 2
// 1133.586 us; speedup vs baseline: 1.0771x; 1.0771x over previous
//
#include <hip/hip_runtime.h>
#include <hip/hip_bf16.h>

#define MM 8192
#define NN 11008
#define KK 4096
#define PKW 2048   // packed int32 words per output row

#define BM 128
#define BN 128
#define BK 64

typedef __attribute__((ext_vector_type(4))) float f32x4;
typedef __attribute__((ext_vector_type(4))) int   i32x4;
typedef __attribute__((ext_vector_type(8))) short s16x8;
typedef __attribute__((ext_vector_type(4))) short s16x4;

typedef __attribute__((address_space(3))) unsigned char        lds_u8;
typedef const __attribute__((address_space(1))) unsigned char  glb_u8;

static __device__ __forceinline__ unsigned short f2bf(float f) {
  union { float f; unsigned int u; } v; v.f = f;
  unsigned int u = v.u;
  u += 0x7fffu + ((u >> 16) & 1u);   // RNE
  return (unsigned short)(u >> 16);
}

// ---------------- preprocessing (writes PRE-SWIZZLED: 16B group g -> g ^ (row&7)
// within each 64-element block, so linear global_load_lds lands data in T2-swizzled
// LDS position; GEMM ds_read applies the same XOR) ----------------

__global__ void int4lin_cvt_x(const float* __restrict__ X, unsigned short* __restrict__ O) {
  const int n8 = (MM * KK) / 8;
  int i = blockIdx.x * blockDim.x + threadIdx.x;
  const int stride = gridDim.x * blockDim.x;
  for (; i < n8; i += stride) {
    const int row = i >> 9;            // KK/8 = 512 groups per row
    const int g   = i & 511;
    const int gs  = (g & ~7) | ((g & 7) ^ (row & 7));   // swizzled group
    const f32x4* p = (const f32x4*)(X + (size_t)i * 8);
    f32x4 a = p[0];
    f32x4 b = p[1];
    s16x8 o;
    o[0] = (short)f2bf(a[0]); o[1] = (short)f2bf(a[1]);
    o[2] = (short)f2bf(a[2]); o[3] = (short)f2bf(a[3]);
    o[4] = (short)f2bf(b[0]); o[5] = (short)f2bf(b[1]);
    o[6] = (short)f2bf(b[2]); o[7] = (short)f2bf(b[3]);
    *(s16x8*)(O + (size_t)row * KK + (size_t)gs * 8) = o;
  }
}

// packed (N, PKW) int32, low byte = two nibbles (low first) -> q in [-7,8] as exact bf16
__global__ void int4lin_deq_w(const int* __restrict__ P, unsigned short* __restrict__ O) {
  const int n4 = (NN * PKW) / 4;     // each i: 4 words -> one 8-elem bf16 group
  int i = blockIdx.x * blockDim.x + threadIdx.x;
  const int stride = gridDim.x * blockDim.x;
  for (; i < n4; i += stride) {
    const int row = i >> 9;            // 512 groups per row
    const int g   = i & 511;
    const int gs  = (g & ~7) | ((g & 7) ^ (row & 7));
    i32x4 v = *(const i32x4*)(P + (size_t)i * 4);
    s16x8 o;
#pragma unroll
    for (int j = 0; j < 4; ++j) {
      int b = v[j];
      o[2 * j]     = (short)f2bf((float)((b & 15) - 7));
      o[2 * j + 1] = (short)f2bf((float)(((b >> 4) & 15) - 7));
    }
    *(s16x8*)(O + (size_t)row * KK + (size_t)gs * 8) = o;
  }
}

// ---------------- GEMM, predequantized bf16 path (m97 structure + T2 swizzle) ----------------

__global__ __launch_bounds__(256) void int4lin_gemm_pre(
    const unsigned short* __restrict__ A,   // M x K bf16, group-swizzled
    const unsigned short* __restrict__ B,   // N x K bf16 (q values, unscaled), group-swizzled
    const float* __restrict__ scale,
    const float* __restrict__ bias,
    float* __restrict__ C)
{
  __shared__ unsigned short As[BM * BK];
  __shared__ unsigned short Bs[BN * BK];

  const int tid  = threadIdx.x;
  const int lane = tid & 63;
  const int wave = tid >> 6;
  const int m0 = blockIdx.y * BM;
  const int n0 = blockIdx.x * BN;
  const int wr = (wave >> 1) * 64;
  const int wc = (wave & 1) * 64;

  f32x4 acc[4][4] = {};

  const int seg0 = wave * 4;
  const int swz  = (lane & 7) << 3;   // ds_read XOR (bf16 elements): slot ^= row&7
  for (int kt = 0; kt < KK; kt += BK) {
#pragma unroll
    for (int i = 0; i < 4; ++i) {
      const int seg  = seg0 + i;              // 16 segments of 1 KiB
      const int flat = seg * 512 + lane * 8;  // element index within tile (linear LDS)
      const int row  = flat >> 6;
      const int col  = flat & 63;
      __builtin_amdgcn_global_load_lds(
          (glb_u8*)(A + (size_t)(m0 + row) * KK + kt + col),
          (lds_u8*)(As + seg * 512), 16, 0, 0);
      __builtin_amdgcn_global_load_lds(
          (glb_u8*)(B + (size_t)(n0 + row) * KK + kt + col),
          (lds_u8*)(Bs + seg * 512), 16, 0, 0);
    }
    __syncthreads();
#pragma unroll
    for (int kk = 0; kk < 2; ++kk) {
      const int rsel = lane & 15;
      const int ksel = ((((lane >> 4) << 3) + kk * 32)) ^ swz;   // swizzled 16B slot
      s16x8 af[4], bfr[4];
#pragma unroll
      for (int m = 0; m < 4; ++m)
        af[m] = *(const s16x8*)(As + (wr + m * 16 + rsel) * BK + ksel);
#pragma unroll
      for (int n = 0; n < 4; ++n)
        bfr[n] = *(const s16x8*)(Bs + (wc + n * 16 + rsel) * BK + ksel);
#pragma unroll
      for (int m = 0; m < 4; ++m)
#pragma unroll
        for (int n = 0; n < 4; ++n)
          acc[m][n] = __builtin_amdgcn_mfma_f32_16x16x32_bf16(af[m], bfr[n], acc[m][n], 0, 0, 0);
    }
    __syncthreads();
  }

  // epilogue: y = acc * scale[col] + bias[col]; C/D map col=lane&15, row=(lane>>4)*4+r
  const int crow = wr + ((lane >> 4) << 2);
  const int ccol = wc + (lane & 15);
#pragma unroll
  for (int n = 0; n < 4; ++n) {
    const int gc = n0 + ccol + n * 16;
    const float sc = scale[gc];
    const float bi = bias[gc];
#pragma unroll
    for (int m = 0; m < 4; ++m) {
      float* cp = C + (size_t)(m0 + crow + m * 16) * NN + gc;
#pragma unroll
      for (int r = 0; r < 4; ++r)
        cp[(size_t)r * NN] = acc[m][n][r] * sc + bi;
    }
  }
}

// ---------------- GEMM, inline-conversion fallback (no workspace needed) ----------------

__global__ __launch_bounds__(256) void int4lin_gemm_inline(
    const float* __restrict__ X,
    const int* __restrict__ P,
    const float* __restrict__ scale,
    const float* __restrict__ bias,
    float* __restrict__ C)
{
  __shared__ unsigned short As[BM * BK];
  __shared__ unsigned short Bs[BN * BK];

  const int tid  = threadIdx.x;
  const int lane = tid & 63;
  const int wave = tid >> 6;
  const int m0 = blockIdx.y * BM;
  const int n0 = blockIdx.x * BN;
  const int wr = (wave >> 1) * 64;
  const int wc = (wave & 1) * 64;

  f32x4 acc[4][4] = {};

  for (int kt = 0; kt < KK; kt += BK) {
#pragma unroll
    for (int i = 0; i < 8; ++i) {
      const int idx = i * 256 + tid;
      const int row = idx >> 4;
      const int c   = (idx & 15) << 2;
      f32x4 v = *(const f32x4*)(X + (size_t)(m0 + row) * KK + kt + c);
      s16x4 o;
      o[0] = (short)f2bf(v[0]); o[1] = (short)f2bf(v[1]);
      o[2] = (short)f2bf(v[2]); o[3] = (short)f2bf(v[3]);
      *(s16x4*)(As + row * BK + (c ^ ((row & 7) << 3) & ~3)) = o;  // 4-elem granularity safe: XOR bits [5:3]
    }
#pragma unroll
    for (int i = 0; i < 4; ++i) {
      const int idx = i * 256 + tid;
      const int row = idx >> 3;
      const int c   = (idx & 7) << 3;
      i32x4 v = *(const i32x4*)(P + (size_t)(n0 + row) * PKW + ((kt + c) >> 1));
      s16x8 o;
#pragma unroll
      for (int j = 0; j < 4; ++j) {
        const int b = v[j];
        o[2 * j]     = (short)f2bf((float)((b & 15) - 7));
        o[2 * j + 1] = (short)f2bf((float)(((b >> 4) & 15) - 7));
      }
      *(s16x8*)(Bs + row * BK + (c ^ ((row & 7) << 3))) = o;
    }
    __syncthreads();
#pragma unroll
    for (int kk = 0; kk < 2; ++kk) {
      const int rsel = lane & 15;
      const int ksel = ((((lane >> 4) << 3) + kk * 32)) ^ ((lane & 7) << 3);
      s16x8 af[4], bfr[4];
#pragma unroll
      for (int m = 0; m < 4; ++m)
        af[m] = *(const s16x8*)(As + (wr + m * 16 + rsel) * BK + ksel);
#pragma unroll
      for (int n = 0; n < 4; ++n)
        bfr[n] = *(const s16x8*)(Bs + (wc + n * 16 + rsel) * BK + ksel);
#pragma unroll
      for (int m = 0; m < 4; ++m)
#pragma unroll
        for (int n = 0; n < 4; ++n)
          acc[m][n] = __builtin_amdgcn_mfma_f32_16x16x32_bf16(af[m], bfr[n], acc[m][n], 0, 0, 0);
    }
    __syncthreads();
  }

  const int crow = wr + ((lane >> 4) << 2);
  const int ccol = wc + (lane & 15);
#pragma unroll
  for (int n = 0; n < 4; ++n) {
    const int gc = n0 + ccol + n * 16;
    const float sc = scale[gc];
    const float bi = bias[gc];
#pragma unroll
    for (int m = 0; m < 4; ++m) {
      float* cp = C + (size_t)(m0 + crow + m * 16) * NN + gc;
#pragma unroll
      for (int r = 0; r < 4; ++r)
        cp[(size_t)r * NN] = acc[m][n][r] * sc + bi;
    }
  }
}

// ---------------- launch ----------------

extern "C" void kernel_launch(void* const* d_in, const int* in_sizes, int n_in,
                              void* d_out, int out_size, void* d_ws, size_t ws_size,
                              hipStream_t stream) {
  const float* x      = (const float*)d_in[0];
  const int*   packed = (const int*)d_in[1];
  const float* scale  = (const float*)d_in[2];
  const float* bias   = (const float*)d_in[3];
  float* y = (float*)d_out;

  const size_t nA = (size_t)MM * KK * sizeof(unsigned short);   // 64 MiB
  const size_t nB = (size_t)NN * KK * sizeof(unsigned short);   // ~86 MiB
  dim3 grid(NN / BN, MM / BM);   // 86 x 64

  if (ws_size >= nA + nB) {
    unsigned short* xb = (unsigned short*)d_ws;
    unsigned short* wb = (unsigned short*)((char*)d_ws + nA);
    int4lin_cvt_x<<<2048, 256, 0, stream>>>(x, xb);
    int4lin_deq_w<<<2048, 256, 0, stream>>>(packed, wb);
    int4lin_gemm_pre<<<grid, 256, 0, stream>>>(xb, wb, scale, bias, y);
  } else {
    int4lin_gemm_inline<<<grid, 256, 0, stream>>>(x, packed, scale, bias, y);
  }
}

// Round 3
// 944.891 us; speedup vs baseline: 1.2922x; 1.1997x over previous
//
#include <hip/hip_runtime.h>
#include <hip/hip_bf16.h>

#define MM 8192
#define NN 11008
#define KK 4096
#define PKW 2048   // packed int32 words per output row

#define BM 256
#define BN 256
#define BK 64

typedef __attribute__((ext_vector_type(4))) float f32x4;
typedef __attribute__((ext_vector_type(4))) int   i32x4;
typedef __attribute__((ext_vector_type(8))) short s16x8;
typedef __attribute__((ext_vector_type(4))) short s16x4;

typedef __attribute__((address_space(3))) unsigned char        lds_u8;
typedef const __attribute__((address_space(1))) unsigned char  glb_u8;

static __device__ __forceinline__ unsigned short f2bf(float f) {
  union { float f; unsigned int u; } v; v.f = f;
  unsigned int u = v.u;
  u += 0x7fffu + ((u >> 16) & 1u);   // RNE
  return (unsigned short)(u >> 16);
}

// ---------------- preprocessing (writes PRE-SWIZZLED: 16B group g -> g ^ (row&7)
// within each 64-element block; GEMM stages linearly via global_load_lds and
// applies the same XOR on ds_read — rule #21 both-sides) ----------------

__global__ void int4lin_cvt_x(const float* __restrict__ X, unsigned short* __restrict__ O) {
  const int n8 = (MM * KK) / 8;
  int i = blockIdx.x * blockDim.x + threadIdx.x;
  const int stride = gridDim.x * blockDim.x;
  for (; i < n8; i += stride) {
    const int row = i >> 9;            // KK/8 = 512 groups per row
    const int g   = i & 511;
    const int gs  = (g & ~7) | ((g & 7) ^ (row & 7));   // swizzled group
    const f32x4* p = (const f32x4*)(X + (size_t)i * 8);
    f32x4 a = p[0];
    f32x4 b = p[1];
    s16x8 o;
    o[0] = (short)f2bf(a[0]); o[1] = (short)f2bf(a[1]);
    o[2] = (short)f2bf(a[2]); o[3] = (short)f2bf(a[3]);
    o[4] = (short)f2bf(b[0]); o[5] = (short)f2bf(b[1]);
    o[6] = (short)f2bf(b[2]); o[7] = (short)f2bf(b[3]);
    *(s16x8*)(O + (size_t)row * KK + (size_t)gs * 8) = o;
  }
}

__global__ void int4lin_deq_w(const int* __restrict__ P, unsigned short* __restrict__ O) {
  const int n4 = (NN * PKW) / 4;     // each i: 4 words -> one 8-elem bf16 group
  int i = blockIdx.x * blockDim.x + threadIdx.x;
  const int stride = gridDim.x * blockDim.x;
  for (; i < n4; i += stride) {
    const int row = i >> 9;            // 512 groups per row
    const int g   = i & 511;
    const int gs  = (g & ~7) | ((g & 7) ^ (row & 7));
    i32x4 v = *(const i32x4*)(P + (size_t)i * 4);
    s16x8 o;
#pragma unroll
    for (int j = 0; j < 4; ++j) {
      int b = v[j];
      o[2 * j]     = (short)f2bf((float)((b & 15) - 7));
      o[2 * j + 1] = (short)f2bf((float)(((b >> 4) & 15) - 7));
    }
    *(s16x8*)(O + (size_t)row * KK + (size_t)gs * 8) = o;
  }
}

// ---------------- 256x256 8-phase GEMM (T1+T2+T3+T4+T5) ----------------

__global__ __launch_bounds__(512, 2) void int4lin_gemm_8p(
    const unsigned short* __restrict__ Aw,   // M x K bf16, group-swizzled
    const unsigned short* __restrict__ Bw,   // N x K bf16 (q values), group-swizzled
    const float* __restrict__ scale,
    const float* __restrict__ bias,
    float* __restrict__ C)
{
  __shared__ unsigned short As[2][BM * BK];   // 2 x 32 KiB
  __shared__ unsigned short Bs[2][BN * BK];   // 2 x 32 KiB  -> 128 KiB total

  const int tid  = threadIdx.x;
  const int lane = tid & 63;
  const int wave = tid >> 6;
  const int wm = wave >> 2;          // 0..1
  const int wn = wave & 3;           // 0..3

  // T1: bijective XCD swizzle (1376 = 8*172); consecutive swz share bm (A-panel in L2)
  const int bid = blockIdx.x;
  const int swz = (bid & 7) * 172 + (bid >> 3);
  const int bm = swz / 43;
  const int bn = swz - bm * 43;
  const size_t m0 = (size_t)bm * BM;
  const size_t n0 = (size_t)bn * BN;

  const int rsel = lane & 15;
  const int gq   = lane >> 4;        // k-group base (0..3)
  const int rx7  = lane & 7;         // T2 swizzle key (== row&7 of fragment rows)

  f32x4 acc[8][4] = {};

  const int arow = wm * 128 + rsel;  // + m*16
  const int brow = wn * 64  + rsel;  // + n*16

  // LDS fragment read with T2 XOR on the 16B slot index
#define LDF(base, row, slot) \
  (*(const s16x8*)((const char*)(base) + (size_t)((row) * 128 + (((slot) ^ rx7) << 4))))

  const int srow = tid >> 3;
  const int scol = (tid & 7) << 3;

  auto stage = [&](int buf, int kt) {
#pragma unroll
    for (int i = 0; i < 4; ++i)
      __builtin_amdgcn_global_load_lds(
          (glb_u8*)(Aw + (m0 + i * 64 + srow) * KK + kt + scol),
          (lds_u8*)((char*)&As[buf][0] + i * 8192 + tid * 16), 16, 0, 0);
#pragma unroll
    for (int i = 0; i < 4; ++i)
      __builtin_amdgcn_global_load_lds(
          (glb_u8*)(Bw + (n0 + i * 64 + srow) * KK + kt + scol),
          (lds_u8*)((char*)&Bs[buf][0] + i * 8192 + tid * 16), 16, 0, 0);
  };

  auto ktile = [&](int rbuf, int kt_next, bool do_stage) {
    const unsigned short* Ab = &As[rbuf][0];
    const unsigned short* Bb = &Bs[rbuf][0];
    s16x8 a[4][2], b0[2][2], b1[2][2];

    // ---- phase 1: stage next K-tile (8 loads, max latency cover); read A[0..3], B[0..1]
    if (do_stage) stage(rbuf ^ 1, kt_next);
#pragma unroll
    for (int m = 0; m < 4; ++m)
#pragma unroll
      for (int kk = 0; kk < 2; ++kk)
        a[m][kk] = LDF(Ab, arow + m * 16, gq + 4 * kk);
#pragma unroll
    for (int n = 0; n < 2; ++n)
#pragma unroll
      for (int kk = 0; kk < 2; ++kk)
        b0[n][kk] = LDF(Bb, brow + n * 16, gq + 4 * kk);
    __builtin_amdgcn_s_barrier();
    asm volatile("s_waitcnt lgkmcnt(0)" ::: "memory");
    __builtin_amdgcn_sched_barrier(0);
    __builtin_amdgcn_s_setprio(1);
#pragma unroll
    for (int m = 0; m < 4; ++m)
#pragma unroll
      for (int n = 0; n < 2; ++n)
#pragma unroll
        for (int kk = 0; kk < 2; ++kk)
          acc[m][n] = __builtin_amdgcn_mfma_f32_16x16x32_bf16(a[m][kk], b0[n][kk], acc[m][n], 0, 0, 0);
    __builtin_amdgcn_s_setprio(0);
    __builtin_amdgcn_s_barrier();

    // ---- phase 2: read B[2..3]; compute (m0-3, n2-3)
#pragma unroll
    for (int n = 0; n < 2; ++n)
#pragma unroll
      for (int kk = 0; kk < 2; ++kk)
        b1[n][kk] = LDF(Bb, brow + (n + 2) * 16, gq + 4 * kk);
    __builtin_amdgcn_s_barrier();
    asm volatile("s_waitcnt lgkmcnt(0)" ::: "memory");
    __builtin_amdgcn_sched_barrier(0);
    __builtin_amdgcn_s_setprio(1);
#pragma unroll
    for (int m = 0; m < 4; ++m)
#pragma unroll
      for (int n = 0; n < 2; ++n)
#pragma unroll
        for (int kk = 0; kk < 2; ++kk)
          acc[m][n + 2] = __builtin_amdgcn_mfma_f32_16x16x32_bf16(a[m][kk], b1[n][kk], acc[m][n + 2], 0, 0, 0);
    __builtin_amdgcn_s_setprio(0);
    __builtin_amdgcn_s_barrier();

    // ---- phase 3: read A[4..7]; compute (m4-7, n2-3)
#pragma unroll
    for (int m = 0; m < 4; ++m)
#pragma unroll
      for (int kk = 0; kk < 2; ++kk)
        a[m][kk] = LDF(Ab, arow + (m + 4) * 16, gq + 4 * kk);
    __builtin_amdgcn_s_barrier();
    asm volatile("s_waitcnt lgkmcnt(0)" ::: "memory");
    __builtin_amdgcn_sched_barrier(0);
    __builtin_amdgcn_s_setprio(1);
#pragma unroll
    for (int m = 0; m < 4; ++m)
#pragma unroll
      for (int n = 0; n < 2; ++n)
#pragma unroll
        for (int kk = 0; kk < 2; ++kk)
          acc[m + 4][n + 2] = __builtin_amdgcn_mfma_f32_16x16x32_bf16(a[m][kk], b1[n][kk], acc[m + 4][n + 2], 0, 0, 0);
    __builtin_amdgcn_s_setprio(0);
    __builtin_amdgcn_s_barrier();

    // ---- phase 4: pure MFMA (m4-7, n0-1); then drain this iter's stage + switch
    __builtin_amdgcn_s_setprio(1);
#pragma unroll
    for (int m = 0; m < 4; ++m)
#pragma unroll
      for (int n = 0; n < 2; ++n)
#pragma unroll
        for (int kk = 0; kk < 2; ++kk)
          acc[m + 4][n] = __builtin_amdgcn_mfma_f32_16x16x32_bf16(a[m][kk], b0[n][kk], acc[m + 4][n], 0, 0, 0);
    __builtin_amdgcn_s_setprio(0);
    asm volatile("s_waitcnt vmcnt(0)" ::: "memory");   // loads issued 3 phases ago -> ~free
    __builtin_amdgcn_s_barrier();
  };

  // prologue
  stage(0, 0);
  asm volatile("s_waitcnt vmcnt(0)" ::: "memory");
  __builtin_amdgcn_s_barrier();

#pragma unroll 1
  for (int i = 0; i < 32; ++i) {
    ktile(0, i * 128 + 64, true);
    ktile(1, i * 128 + 128, i < 31);
  }

  // epilogue: y = acc * scale[col] + bias[col]; C/D map col=lane&15, row=gq*4+r
  const size_t crow0 = m0 + wm * 128 + (gq << 2);
  const size_t ccol0 = n0 + wn * 64 + rsel;
#pragma unroll
  for (int n = 0; n < 4; ++n) {
    const size_t gc = ccol0 + n * 16;
    const float sc = scale[gc];
    const float bi = bias[gc];
#pragma unroll
    for (int m = 0; m < 8; ++m) {
      float* cp = C + (crow0 + m * 16) * NN + gc;
#pragma unroll
      for (int r = 0; r < 4; ++r)
        cp[(size_t)r * NN] = acc[m][n][r] * sc + bi;
    }
  }
#undef LDF
}

// ---------------- GEMM, inline-conversion fallback (no workspace needed) ----------------

__global__ __launch_bounds__(256) void int4lin_gemm_inline(
    const float* __restrict__ X,
    const int* __restrict__ P,
    const float* __restrict__ scale,
    const float* __restrict__ bias,
    float* __restrict__ C)
{
  __shared__ unsigned short As[128 * BK];
  __shared__ unsigned short Bs[128 * BK];

  const int tid  = threadIdx.x;
  const int lane = tid & 63;
  const int wave = tid >> 6;
  const int m0 = blockIdx.y * 128;
  const int n0 = blockIdx.x * 128;
  const int wr = (wave >> 1) * 64;
  const int wc = (wave & 1) * 64;

  f32x4 acc[4][4] = {};

  for (int kt = 0; kt < KK; kt += BK) {
#pragma unroll
    for (int i = 0; i < 8; ++i) {
      const int idx = i * 256 + tid;
      const int row = idx >> 4;
      const int c   = (idx & 15) << 2;
      f32x4 v = *(const f32x4*)(X + (size_t)(m0 + row) * KK + kt + c);
      s16x4 o;
      o[0] = (short)f2bf(v[0]); o[1] = (short)f2bf(v[1]);
      o[2] = (short)f2bf(v[2]); o[3] = (short)f2bf(v[3]);
      *(s16x4*)(As + row * BK + (c ^ ((row & 7) << 3))) = o;
    }
#pragma unroll
    for (int i = 0; i < 4; ++i) {
      const int idx = i * 256 + tid;
      const int row = idx >> 3;
      const int c   = (idx & 7) << 3;
      i32x4 v = *(const i32x4*)(P + (size_t)(n0 + row) * PKW + ((kt + c) >> 1));
      s16x8 o;
#pragma unroll
      for (int j = 0; j < 4; ++j) {
        const int b = v[j];
        o[2 * j]     = (short)f2bf((float)((b & 15) - 7));
        o[2 * j + 1] = (short)f2bf((float)(((b >> 4) & 15) - 7));
      }
      *(s16x8*)(Bs + row * BK + (c ^ ((row & 7) << 3))) = o;
    }
    __syncthreads();
#pragma unroll
    for (int kk = 0; kk < 2; ++kk) {
      const int rsel = lane & 15;
      const int ksel = ((((lane >> 4) << 3) + kk * 32)) ^ ((lane & 7) << 3);
      s16x8 af[4], bfr[4];
#pragma unroll
      for (int m = 0; m < 4; ++m)
        af[m] = *(const s16x8*)(As + (wr + m * 16 + rsel) * BK + ksel);
#pragma unroll
      for (int n = 0; n < 4; ++n)
        bfr[n] = *(const s16x8*)(Bs + (wc + n * 16 + rsel) * BK + ksel);
#pragma unroll
      for (int m = 0; m < 4; ++m)
#pragma unroll
        for (int n = 0; n < 4; ++n)
          acc[m][n] = __builtin_amdgcn_mfma_f32_16x16x32_bf16(af[m], bfr[n], acc[m][n], 0, 0, 0);
    }
    __syncthreads();
  }

  const int crow = wr + ((lane >> 4) << 2);
  const int ccol = wc + (lane & 15);
#pragma unroll
  for (int n = 0; n < 4; ++n) {
    const int gc = n0 + ccol + n * 16;
    const float sc = scale[gc];
    const float bi = bias[gc];
#pragma unroll
    for (int m = 0; m < 4; ++m) {
      float* cp = C + (size_t)(m0 + crow + m * 16) * NN + gc;
#pragma unroll
      for (int r = 0; r < 4; ++r)
        cp[(size_t)r * NN] = acc[m][n][r] * sc + bi;
    }
  }
}

// ---------------- launch ----------------

extern "C" void kernel_launch(void* const* d_in, const int* in_sizes, int n_in,
                              void* d_out, int out_size, void* d_ws, size_t ws_size,
                              hipStream_t stream) {
  const float* x      = (const float*)d_in[0];
  const int*   packed = (const int*)d_in[1];
  const float* scale  = (const float*)d_in[2];
  const float* bias   = (const float*)d_in[3];
  float* y = (float*)d_out;

  const size_t nA = (size_t)MM * KK * sizeof(unsigned short);   // 64 MiB
  const size_t nB = (size_t)NN * KK * sizeof(unsigned short);   // ~86 MiB

  if (ws_size >= nA + nB) {
    unsigned short* xb = (unsigned short*)d_ws;
    unsigned short* wb = (unsigned short*)((char*)d_ws + nA);
    int4lin_cvt_x<<<2048, 256, 0, stream>>>(x, xb);
    int4lin_deq_w<<<2048, 256, 0, stream>>>(packed, wb);
    int4lin_gemm_8p<<<(NN / BN) * (MM / BM), 512, 0, stream>>>(xb, wb, scale, bias, y);
  } else {
    dim3 grid(NN / 128, MM / 128);
    int4lin_gemm_inline<<<grid, 256, 0, stream>>>(x, packed, scale, bias, y);
  }
}

// Round 4
// 943.284 us; speedup vs baseline: 1.2944x; 1.0017x over previous
//
#include <hip/hip_runtime.h>
#include <hip/hip_bf16.h>

#define MM 8192
#define NN 11008
#define KK 4096
#define PKW 2048   // packed int32 words per output row

#define BM 256
#define BN 256
#define BK 64

typedef __attribute__((ext_vector_type(4))) float f32x4;
typedef __attribute__((ext_vector_type(4))) int   i32x4;
typedef __attribute__((ext_vector_type(8))) short s16x8;
typedef __attribute__((ext_vector_type(4))) short s16x4;

typedef __attribute__((address_space(3))) unsigned char        lds_u8;
typedef const __attribute__((address_space(1))) unsigned char  glb_u8;

static __device__ __forceinline__ unsigned short f2bf(float f) {
  union { float f; unsigned int u; } v; v.f = f;
  unsigned int u = v.u;
  u += 0x7fffu + ((u >> 16) & 1u);   // RNE
  return (unsigned short)(u >> 16);
}

// ---------------- preprocessing (writes PRE-SWIZZLED: 16B group g -> g ^ (row&7)
// within each 64-element block; GEMM stages linearly via global_load_lds and
// applies the same XOR on ds_read — rule #21 both-sides) ----------------

__global__ void int4lin_cvt_x(const float* __restrict__ X, unsigned short* __restrict__ O) {
  const int n8 = (MM * KK) / 8;
  int i = blockIdx.x * blockDim.x + threadIdx.x;
  const int stride = gridDim.x * blockDim.x;
  for (; i < n8; i += stride) {
    const int row = i >> 9;            // KK/8 = 512 groups per row
    const int g   = i & 511;
    const int gs  = (g & ~7) | ((g & 7) ^ (row & 7));   // swizzled group
    const f32x4* p = (const f32x4*)(X + (size_t)i * 8);
    f32x4 a = p[0];
    f32x4 b = p[1];
    s16x8 o;
    o[0] = (short)f2bf(a[0]); o[1] = (short)f2bf(a[1]);
    o[2] = (short)f2bf(a[2]); o[3] = (short)f2bf(a[3]);
    o[4] = (short)f2bf(b[0]); o[5] = (short)f2bf(b[1]);
    o[6] = (short)f2bf(b[2]); o[7] = (short)f2bf(b[3]);
    *(s16x8*)(O + (size_t)row * KK + (size_t)gs * 8) = o;
  }
}

__global__ void int4lin_deq_w(const int* __restrict__ P, unsigned short* __restrict__ O) {
  const int n4 = (NN * PKW) / 4;     // each i: 4 words -> one 8-elem bf16 group
  int i = blockIdx.x * blockDim.x + threadIdx.x;
  const int stride = gridDim.x * blockDim.x;
  for (; i < n4; i += stride) {
    const int row = i >> 9;            // 512 groups per row
    const int g   = i & 511;
    const int gs  = (g & ~7) | ((g & 7) ^ (row & 7));
    i32x4 v = *(const i32x4*)(P + (size_t)i * 4);
    s16x8 o;
#pragma unroll
    for (int j = 0; j < 4; ++j) {
      int b = v[j];
      o[2 * j]     = (short)f2bf((float)((b & 15) - 7));
      o[2 * j + 1] = (short)f2bf((float)(((b >> 4) & 15) - 7));
    }
    *(s16x8*)(O + (size_t)row * KK + (size_t)gs * 8) = o;
  }
}

// ---------------- 256x256 8-phase GEMM (T1+T2+T3+T4+T5; kk-per-phase) ----------------

__global__ __launch_bounds__(512, 2) void int4lin_gemm_8p(
    const unsigned short* __restrict__ Aw,   // M x K bf16, group-swizzled
    const unsigned short* __restrict__ Bw,   // N x K bf16 (q values), group-swizzled
    const float* __restrict__ scale,
    const float* __restrict__ bias,
    float* __restrict__ C)
{
  __shared__ unsigned short As[2][BM * BK];   // 2 x 32 KiB
  __shared__ unsigned short Bs[2][BN * BK];   // 2 x 32 KiB  -> 128 KiB total

  const int tid  = threadIdx.x;
  const int lane = tid & 63;
  const int wave = tid >> 6;
  const int wm = wave >> 2;          // 0..1
  const int wn = wave & 3;           // 0..3

  // T1: bijective XCD swizzle (1376 = 8*172); consecutive swz share bm (A-panel in L2)
  const int bid = blockIdx.x;
  const int swz = (bid & 7) * 172 + (bid >> 3);
  const int bm = swz / 43;
  const int bn = swz - bm * 43;
  const size_t m0 = (size_t)bm * BM;
  const size_t n0 = (size_t)bn * BN;

  const int rsel = lane & 15;
  const int gq   = lane >> 4;        // k-slot base (0..3); kk1 slot = gq+4
  const int rx7  = lane & 7;         // T2 swizzle key (== row&7 of fragment rows)

  f32x4 acc[8][4] = {};

  const int arow = wm * 128 + rsel;  // + m*16
  const int brow = wn * 64  + rsel;  // + n*16

  // LDS fragment read with T2 XOR on the 16B slot index
#define LDF(base, row, slot) \
  (*(const s16x8*)((const char*)(base) + (size_t)((row) * 128 + (((slot) ^ rx7) << 4))))

  const int srow = tid >> 3;
  const int scol = (tid & 7) << 3;

  auto stage_a = [&](int buf, int kt) {
#pragma unroll
    for (int i = 0; i < 4; ++i)
      __builtin_amdgcn_global_load_lds(
          (glb_u8*)(Aw + (m0 + i * 64 + srow) * KK + kt + scol),
          (lds_u8*)((char*)&As[buf][0] + i * 8192 + tid * 16), 16, 0, 0);
  };
  auto stage_b = [&](int buf, int kt) {
#pragma unroll
    for (int i = 0; i < 4; ++i)
      __builtin_amdgcn_global_load_lds(
          (glb_u8*)(Bw + (n0 + i * 64 + srow) * KK + kt + scol),
          (lds_u8*)((char*)&Bs[buf][0] + i * 8192 + tid * 16), 16, 0, 0);
  };

  auto ktile = [&](int rbuf, int kt_next, bool do_stage) {
    const unsigned short* Ab = &As[rbuf][0];
    const unsigned short* Bb = &Bs[rbuf][0];
    s16x8 av[4], b0[4], b1[4];

    // ---- P1: stage A(t+1); read a[m0-3]kk0 + b[all]kk0; MFMA kk0 x m0-3 x n0-3
    if (do_stage) stage_a(rbuf ^ 1, kt_next);
#pragma unroll
    for (int m = 0; m < 4; ++m) av[m] = LDF(Ab, arow + m * 16, gq);
#pragma unroll
    for (int n = 0; n < 4; ++n) b0[n] = LDF(Bb, brow + n * 16, gq);
    __builtin_amdgcn_s_barrier();
    asm volatile("s_waitcnt lgkmcnt(0)" ::: "memory");
    __builtin_amdgcn_s_setprio(1);
#pragma unroll
    for (int m = 0; m < 4; ++m)
#pragma unroll
      for (int n = 0; n < 4; ++n)
        acc[m][n] = __builtin_amdgcn_mfma_f32_16x16x32_bf16(av[m], b0[n], acc[m][n], 0, 0, 0);
    __builtin_amdgcn_s_setprio(0);
    __builtin_amdgcn_s_barrier();

    // ---- P2: stage B(t+1); read a[m0-3]kk1 + b[all]kk1; MFMA kk1 x m0-3 x n0-3
    if (do_stage) stage_b(rbuf ^ 1, kt_next);
    {
      s16x8 av1[4];
#pragma unroll
      for (int m = 0; m < 4; ++m) av1[m] = LDF(Ab, arow + m * 16, gq + 4);
#pragma unroll
      for (int n = 0; n < 4; ++n) b1[n] = LDF(Bb, brow + n * 16, gq + 4);
      __builtin_amdgcn_s_barrier();
      asm volatile("s_waitcnt lgkmcnt(0)" ::: "memory");
      __builtin_amdgcn_s_setprio(1);
#pragma unroll
      for (int m = 0; m < 4; ++m)
#pragma unroll
        for (int n = 0; n < 4; ++n)
          acc[m][n] = __builtin_amdgcn_mfma_f32_16x16x32_bf16(av1[m], b1[n], acc[m][n], 0, 0, 0);
      __builtin_amdgcn_s_setprio(0);
      __builtin_amdgcn_s_barrier();
    }

    // ---- P3: read a[m4-7]kk0; MFMA kk0 x m4-7 x n0-3 (b0 still live)
#pragma unroll
    for (int m = 0; m < 4; ++m) av[m] = LDF(Ab, arow + (m + 4) * 16, gq);
    __builtin_amdgcn_s_barrier();
    asm volatile("s_waitcnt lgkmcnt(0)" ::: "memory");
    __builtin_amdgcn_s_setprio(1);
#pragma unroll
    for (int m = 0; m < 4; ++m)
#pragma unroll
      for (int n = 0; n < 4; ++n)
        acc[m + 4][n] = __builtin_amdgcn_mfma_f32_16x16x32_bf16(av[m], b0[n], acc[m + 4][n], 0, 0, 0);
    __builtin_amdgcn_s_setprio(0);
    __builtin_amdgcn_s_barrier();

    // ---- P4: read a[m4-7]kk1; MFMA kk1 x m4-7 x n0-3 (b1 still live); drain; switch
#pragma unroll
    for (int m = 0; m < 4; ++m) av[m] = LDF(Ab, arow + (m + 4) * 16, gq + 4);
    __builtin_amdgcn_s_barrier();
    asm volatile("s_waitcnt lgkmcnt(0)" ::: "memory");
    __builtin_amdgcn_s_setprio(1);
#pragma unroll
    for (int m = 0; m < 4; ++m)
#pragma unroll
      for (int n = 0; n < 4; ++n)
        acc[m + 4][n] = __builtin_amdgcn_mfma_f32_16x16x32_bf16(av[m], b1[n], acc[m + 4][n], 0, 0, 0);
    __builtin_amdgcn_s_setprio(0);
    asm volatile("s_waitcnt vmcnt(0)" ::: "memory");   // stage issued at P1/P2 -> 2-3 phases cover
    __builtin_amdgcn_s_barrier();
  };

  // prologue
  stage_a(0, 0);
  stage_b(0, 0);
  asm volatile("s_waitcnt vmcnt(0)" ::: "memory");
  __builtin_amdgcn_s_barrier();

#pragma unroll 1
  for (int i = 0; i < 32; ++i) {
    ktile(0, i * 128 + 64, true);
    ktile(1, i * 128 + 128, i < 31);
  }

  // epilogue: y = acc * scale[col] + bias[col]; C/D map col=lane&15, row=gq*4+r
  const size_t crow0 = m0 + wm * 128 + (gq << 2);
  const size_t ccol0 = n0 + wn * 64 + rsel;
#pragma unroll
  for (int n = 0; n < 4; ++n) {
    const size_t gc = ccol0 + n * 16;
    const float sc = scale[gc];
    const float bi = bias[gc];
#pragma unroll
    for (int m = 0; m < 8; ++m) {
      float* cp = C + (crow0 + m * 16) * NN + gc;
#pragma unroll
      for (int r = 0; r < 4; ++r)
        cp[(size_t)r * NN] = acc[m][n][r] * sc + bi;
    }
  }
#undef LDF
}

// ---------------- GEMM, inline-conversion fallback (no workspace needed) ----------------

__global__ __launch_bounds__(256) void int4lin_gemm_inline(
    const float* __restrict__ X,
    const int* __restrict__ P,
    const float* __restrict__ scale,
    const float* __restrict__ bias,
    float* __restrict__ C)
{
  __shared__ unsigned short As[128 * BK];
  __shared__ unsigned short Bs[128 * BK];

  const int tid  = threadIdx.x;
  const int lane = tid & 63;
  const int wave = tid >> 6;
  const int m0 = blockIdx.y * 128;
  const int n0 = blockIdx.x * 128;
  const int wr = (wave >> 1) * 64;
  const int wc = (wave & 1) * 64;

  f32x4 acc[4][4] = {};

  for (int kt = 0; kt < KK; kt += BK) {
#pragma unroll
    for (int i = 0; i < 8; ++i) {
      const int idx = i * 256 + tid;
      const int row = idx >> 4;
      const int c   = (idx & 15) << 2;
      f32x4 v = *(const f32x4*)(X + (size_t)(m0 + row) * KK + kt + c);
      s16x4 o;
      o[0] = (short)f2bf(v[0]); o[1] = (short)f2bf(v[1]);
      o[2] = (short)f2bf(v[2]); o[3] = (short)f2bf(v[3]);
      *(s16x4*)(As + row * BK + (c ^ ((row & 7) << 3))) = o;
    }
#pragma unroll
    for (int i = 0; i < 4; ++i) {
      const int idx = i * 256 + tid;
      const int row = idx >> 3;
      const int c   = (idx & 7) << 3;
      i32x4 v = *(const i32x4*)(P + (size_t)(n0 + row) * PKW + ((kt + c) >> 1));
      s16x8 o;
#pragma unroll
      for (int j = 0; j < 4; ++j) {
        const int b = v[j];
        o[2 * j]     = (short)f2bf((float)((b & 15) - 7));
        o[2 * j + 1] = (short)f2bf((float)(((b >> 4) & 15) - 7));
      }
      *(s16x8*)(Bs + row * BK + (c ^ ((row & 7) << 3))) = o;
    }
    __syncthreads();
#pragma unroll
    for (int kk = 0; kk < 2; ++kk) {
      const int rsel = lane & 15;
      const int ksel = ((((lane >> 4) << 3) + kk * 32)) ^ ((lane & 7) << 3);
      s16x8 af[4], bfr[4];
#pragma unroll
      for (int m = 0; m < 4; ++m)
        af[m] = *(const s16x8*)(As + (wr + m * 16 + rsel) * BK + ksel);
#pragma unroll
      for (int n = 0; n < 4; ++n)
        bfr[n] = *(const s16x8*)(Bs + (wc + n * 16 + rsel) * BK + ksel);
#pragma unroll
      for (int m = 0; m < 4; ++m)
#pragma unroll
        for (int n = 0; n < 4; ++n)
          acc[m][n] = __builtin_amdgcn_mfma_f32_16x16x32_bf16(af[m], bfr[n], acc[m][n], 0, 0, 0);
    }
    __syncthreads();
  }

  const int crow = wr + ((lane >> 4) << 2);
  const int ccol = wc + (lane & 15);
#pragma unroll
  for (int n = 0; n < 4; ++n) {
    const int gc = n0 + ccol + n * 16;
    const float sc = scale[gc];
    const float bi = bias[gc];
#pragma unroll
    for (int m = 0; m < 4; ++m) {
      float* cp = C + (size_t)(m0 + crow + m * 16) * NN + gc;
#pragma unroll
      for (int r = 0; r < 4; ++r)
        cp[(size_t)r * NN] = acc[m][n][r] * sc + bi;
    }
  }
}

// ---------------- launch ----------------

extern "C" void kernel_launch(void* const* d_in, const int* in_sizes, int n_in,
                              void* d_out, int out_size, void* d_ws, size_t ws_size,
                              hipStream_t stream) {
  const float* x      = (const float*)d_in[0];
  const int*   packed = (const int*)d_in[1];
  const float* scale  = (const float*)d_in[2];
  const float* bias   = (const float*)d_in[3];
  float* y = (float*)d_out;

  const size_t nA = (size_t)MM * KK * sizeof(unsigned short);   // 64 MiB
  const size_t nB = (size_t)NN * KK * sizeof(unsigned short);   // ~86 MiB

  if (ws_size >= nA + nB) {
    unsigned short* xb = (unsigned short*)d_ws;
    unsigned short* wb = (unsigned short*)((char*)d_ws + nA);
    int4lin_cvt_x<<<2048, 256, 0, stream>>>(x, xb);
    int4lin_deq_w<<<2048, 256, 0, stream>>>(packed, wb);
    int4lin_gemm_8p<<<(NN / BN) * (MM / BM), 512, 0, stream>>>(xb, wb, scale, bias, y);
  } else {
    dim3 grid(NN / 128, MM / 128);
    int4lin_gemm_inline<<<grid, 256, 0, stream>>>(x, packed, scale, bias, y);
  }
}

// Round 5
// 937.503 us; speedup vs baseline: 1.3024x; 1.0062x over previous
//
#include <hip/hip_runtime.h>
#include <hip/hip_bf16.h>

#define MM 8192
#define NN 11008
#define KK 4096
#define PKW 2048   // packed int32 words per output row

#define BM 256
#define BN 256
#define BK 64
#define NT (KK / BK)   // 64 K-tiles

typedef __attribute__((ext_vector_type(4))) float f32x4;
typedef __attribute__((ext_vector_type(4))) int   i32x4;
typedef __attribute__((ext_vector_type(8))) short s16x8;
typedef __attribute__((ext_vector_type(4))) short s16x4;

typedef __attribute__((address_space(3))) unsigned char        lds_u8;
typedef const __attribute__((address_space(1))) unsigned char  glb_u8;

static __device__ __forceinline__ unsigned short f2bf(float f) {
  union { float f; unsigned int u; } v; v.f = f;
  unsigned int u = v.u;
  u += 0x7fffu + ((u >> 16) & 1u);   // RNE
  return (unsigned short)(u >> 16);
}

// ---------------- preprocessing (writes PRE-SWIZZLED: 16B group g -> g ^ (row&7)
// within each 64-element block; GEMM stages linearly via global_load_lds and
// applies the same XOR on ds_read — rule #21 both-sides) ----------------

__global__ void int4lin_cvt_x(const float* __restrict__ X, unsigned short* __restrict__ O) {
  const int n8 = (MM * KK) / 8;
  int i = blockIdx.x * blockDim.x + threadIdx.x;
  const int stride = gridDim.x * blockDim.x;
  for (; i < n8; i += stride) {
    const int row = i >> 9;            // KK/8 = 512 groups per row
    const int g   = i & 511;
    const int gs  = (g & ~7) | ((g & 7) ^ (row & 7));   // swizzled group
    const f32x4* p = (const f32x4*)(X + (size_t)i * 8);
    f32x4 a = p[0];
    f32x4 b = p[1];
    s16x8 o;
    o[0] = (short)f2bf(a[0]); o[1] = (short)f2bf(a[1]);
    o[2] = (short)f2bf(a[2]); o[3] = (short)f2bf(a[3]);
    o[4] = (short)f2bf(b[0]); o[5] = (short)f2bf(b[1]);
    o[6] = (short)f2bf(b[2]); o[7] = (short)f2bf(b[3]);
    *(s16x8*)(O + (size_t)row * KK + (size_t)gs * 8) = o;
  }
}

__global__ void int4lin_deq_w(const int* __restrict__ P, unsigned short* __restrict__ O) {
  const int n4 = (NN * PKW) / 4;     // each i: 4 words -> one 8-elem bf16 group
  int i = blockIdx.x * blockDim.x + threadIdx.x;
  const int stride = gridDim.x * blockDim.x;
  for (; i < n4; i += stride) {
    const int row = i >> 9;            // 512 groups per row
    const int g   = i & 511;
    const int gs  = (g & ~7) | ((g & 7) ^ (row & 7));
    i32x4 v = *(const i32x4*)(P + (size_t)i * 4);
    s16x8 o;
#pragma unroll
    for (int j = 0; j < 4; ++j) {
      int b = v[j];
      o[2 * j]     = (short)f2bf((float)((b & 15) - 7));
      o[2 * j + 1] = (short)f2bf((float)(((b >> 4) & 15) - 7));
    }
    *(s16x8*)(O + (size_t)row * KK + (size_t)gs * 8) = o;
  }
}

// ---------------- 256x256 GEMM, T4 counted-vmcnt ring (T1+T2+T3+T4+T5) ----------------
//
// Staging ring (per-wave ledger, 8 gloads/tile: A-quarters q0..q3 @1 each, B @4):
//   P1 of t: stage A(t+1) late quarters (q1,q3)   [freed by end-P4 barrier of t-1]
//   P3 of t: stage B(t+2) all 4 quarters          [freed by end-P2 barrier of t]
//   P4 of t: stage A(t+2) early quarters (q0,q2)  [freed by end-P2 barrier of t]
// Wait: end-P4 of t: vmcnt(6) — tile t+1's newest load (P1 of t) has exactly
// 6 loads issued after it (4 B + 2 A at P3/P4); its 6 loads stay in flight.

__global__ __launch_bounds__(512, 2) void int4lin_gemm_8p(
    const unsigned short* __restrict__ Aw,   // M x K bf16, group-swizzled
    const unsigned short* __restrict__ Bw,   // N x K bf16 (q values), group-swizzled
    const float* __restrict__ scale,
    const float* __restrict__ bias,
    float* __restrict__ C)
{
  __shared__ unsigned short As[2][BM * BK];   // 2 x 32 KiB
  __shared__ unsigned short Bs[2][BN * BK];   // 2 x 32 KiB  -> 128 KiB total

  const int tid  = threadIdx.x;
  const int lane = tid & 63;
  const int wave = tid >> 6;
  const int wm = wave >> 2;          // 0..1
  const int wn = wave & 3;           // 0..3

  // T1: bijective XCD swizzle (1376 = 8*172); consecutive swz share bm (A-panel in L2)
  const int bid = blockIdx.x;
  const int swz = (bid & 7) * 172 + (bid >> 3);
  const int bm = swz / 43;
  const int bn = swz - bm * 43;
  const size_t m0 = (size_t)bm * BM;
  const size_t n0 = (size_t)bn * BN;

  const int rsel = lane & 15;
  const int gq   = lane >> 4;        // k-slot base (0..3); kk1 slot = gq+4
  const int rx7  = lane & 7;         // T2 swizzle key (== row&7 of fragment rows)

  f32x4 acc[8][4] = {};

  const int arow = wm * 128 + rsel;  // + m*16
  const int brow = wn * 64  + rsel;  // + n*16

  // LDS fragment read with T2 XOR on the 16B slot index
#define LDF(base, row, slot) \
  (*(const s16x8*)((const char*)(base) + (size_t)((row) * 128 + (((slot) ^ rx7) << 4))))

  const int srow = tid >> 3;          // 0..63
  const int scol = (tid & 7) << 3;    // bf16 col, x8

  // one 64x64 quarter = 8 KiB = 1 global_load_lds per thread
  auto stage_a_q = [&](int buf, int kt, int q) {
    __builtin_amdgcn_global_load_lds(
        (glb_u8*)(Aw + (m0 + q * 64 + srow) * KK + kt + scol),
        (lds_u8*)((char*)&As[buf][0] + q * 8192 + tid * 16), 16, 0, 0);
  };
  auto stage_b_q = [&](int buf, int kt, int q) {
    __builtin_amdgcn_global_load_lds(
        (glb_u8*)(Bw + (n0 + q * 64 + srow) * KK + kt + scol),
        (lds_u8*)((char*)&Bs[buf][0] + q * 8192 + tid * 16), 16, 0, 0);
  };

  // -------- prologue: tile0 fully (8), tile1 partially (6); vmcnt(6) --------
#pragma unroll
  for (int q = 0; q < 4; ++q) stage_b_q(0, 0, q);
  stage_a_q(0, 0, 0); stage_a_q(0, 0, 2);
  stage_a_q(0, 0, 1); stage_a_q(0, 0, 3);
#pragma unroll
  for (int q = 0; q < 4; ++q) stage_b_q(1, BK, q);
  stage_a_q(1, BK, 0); stage_a_q(1, BK, 2);
  asm volatile("s_waitcnt vmcnt(6)" ::: "memory");
  __builtin_amdgcn_s_barrier();

#pragma unroll 1
  for (int t = 0; t < NT; ++t) {
    const int rbuf = t & 1;
    const unsigned short* Ab = &As[rbuf][0];
    const unsigned short* Bb = &Bs[rbuf][0];
    s16x8 a0[4], a1[4], b0[4], b1[4];

    // ---- P1: read a[m0-3]kk0 + b[all]kk0; stage A(t+1) late; MFMA
#pragma unroll
    for (int m = 0; m < 4; ++m) a0[m] = LDF(Ab, arow + m * 16, gq);
#pragma unroll
    for (int n = 0; n < 4; ++n) b0[n] = LDF(Bb, brow + n * 16, gq);
    if (t + 1 < NT) {
      stage_a_q(rbuf ^ 1, (t + 1) * BK, 1);
      stage_a_q(rbuf ^ 1, (t + 1) * BK, 3);
    }
    __builtin_amdgcn_s_barrier();
    asm volatile("s_waitcnt lgkmcnt(0)" ::: "memory");
    __builtin_amdgcn_s_setprio(1);
#pragma unroll
    for (int m = 0; m < 4; ++m)
#pragma unroll
      for (int n = 0; n < 4; ++n)
        acc[m][n] = __builtin_amdgcn_mfma_f32_16x16x32_bf16(a0[m], b0[n], acc[m][n], 0, 0, 0);
    __builtin_amdgcn_s_setprio(0);
    __builtin_amdgcn_s_barrier();

    // ---- P2: read a[m0-3]kk1 + b[all]kk1; MFMA. After this barrier B + A-early free.
#pragma unroll
    for (int m = 0; m < 4; ++m) a1[m] = LDF(Ab, arow + m * 16, gq + 4);
#pragma unroll
    for (int n = 0; n < 4; ++n) b1[n] = LDF(Bb, brow + n * 16, gq + 4);
    __builtin_amdgcn_s_barrier();
    asm volatile("s_waitcnt lgkmcnt(0)" ::: "memory");
    __builtin_amdgcn_s_setprio(1);
#pragma unroll
    for (int m = 0; m < 4; ++m)
#pragma unroll
      for (int n = 0; n < 4; ++n)
        acc[m][n] = __builtin_amdgcn_mfma_f32_16x16x32_bf16(a1[m], b1[n], acc[m][n], 0, 0, 0);
    __builtin_amdgcn_s_setprio(0);
    __builtin_amdgcn_s_barrier();

    // ---- P3: read a[m4-7]kk0; stage B(t+2); MFMA (b0 live in regs)
#pragma unroll
    for (int m = 0; m < 4; ++m) a0[m] = LDF(Ab, arow + (m + 4) * 16, gq);
    if (t + 2 < NT) {
#pragma unroll
      for (int q = 0; q < 4; ++q) stage_b_q(rbuf, (t + 2) * BK, q);
    }
    __builtin_amdgcn_s_barrier();
    asm volatile("s_waitcnt lgkmcnt(0)" ::: "memory");
    __builtin_amdgcn_s_setprio(1);
#pragma unroll
    for (int m = 0; m < 4; ++m)
#pragma unroll
      for (int n = 0; n < 4; ++n)
        acc[m + 4][n] = __builtin_amdgcn_mfma_f32_16x16x32_bf16(a0[m], b0[n], acc[m + 4][n], 0, 0, 0);
    __builtin_amdgcn_s_setprio(0);
    __builtin_amdgcn_s_barrier();

    // ---- P4: read a[m4-7]kk1; stage A(t+2) early; MFMA; counted wait; barrier
#pragma unroll
    for (int m = 0; m < 4; ++m) a1[m] = LDF(Ab, arow + (m + 4) * 16, gq + 4);
    if (t + 2 < NT) {
      stage_a_q(rbuf, (t + 2) * BK, 0);
      stage_a_q(rbuf, (t + 2) * BK, 2);
    }
    __builtin_amdgcn_s_barrier();
    asm volatile("s_waitcnt lgkmcnt(0)" ::: "memory");
    __builtin_amdgcn_s_setprio(1);
#pragma unroll
    for (int m = 0; m < 4; ++m)
#pragma unroll
      for (int n = 0; n < 4; ++n)
        acc[m + 4][n] = __builtin_amdgcn_mfma_f32_16x16x32_bf16(a1[m], b1[n], acc[m + 4][n], 0, 0, 0);
    __builtin_amdgcn_s_setprio(0);
    if (t < NT - 2)       asm volatile("s_waitcnt vmcnt(6)" ::: "memory");
    else if (t == NT - 2) asm volatile("s_waitcnt vmcnt(0)" ::: "memory");
    __builtin_amdgcn_s_barrier();
  }

  // epilogue: y = acc * scale[col] + bias[col]; C/D map col=lane&15, row=gq*4+r
  const size_t crow0 = m0 + wm * 128 + (gq << 2);
  const size_t ccol0 = n0 + wn * 64 + rsel;
#pragma unroll
  for (int n = 0; n < 4; ++n) {
    const size_t gc = ccol0 + n * 16;
    const float sc = scale[gc];
    const float bi = bias[gc];
#pragma unroll
    for (int m = 0; m < 8; ++m) {
      float* cp = C + (crow0 + m * 16) * NN + gc;
#pragma unroll
      for (int r = 0; r < 4; ++r)
        cp[(size_t)r * NN] = acc[m][n][r] * sc + bi;
    }
  }
#undef LDF
}

// ---------------- GEMM, inline-conversion fallback (no workspace needed) ----------------

__global__ __launch_bounds__(256) void int4lin_gemm_inline(
    const float* __restrict__ X,
    const int* __restrict__ P,
    const float* __restrict__ scale,
    const float* __restrict__ bias,
    float* __restrict__ C)
{
  __shared__ unsigned short As[128 * BK];
  __shared__ unsigned short Bs[128 * BK];

  const int tid  = threadIdx.x;
  const int lane = tid & 63;
  const int wave = tid >> 6;
  const int m0 = blockIdx.y * 128;
  const int n0 = blockIdx.x * 128;
  const int wr = (wave >> 1) * 64;
  const int wc = (wave & 1) * 64;

  f32x4 acc[4][4] = {};

  for (int kt = 0; kt < KK; kt += BK) {
#pragma unroll
    for (int i = 0; i < 8; ++i) {
      const int idx = i * 256 + tid;
      const int row = idx >> 4;
      const int c   = (idx & 15) << 2;
      f32x4 v = *(const f32x4*)(X + (size_t)(m0 + row) * KK + kt + c);
      s16x4 o;
      o[0] = (short)f2bf(v[0]); o[1] = (short)f2bf(v[1]);
      o[2] = (short)f2bf(v[2]); o[3] = (short)f2bf(v[3]);
      *(s16x4*)(As + row * BK + (c ^ ((row & 7) << 3))) = o;
    }
#pragma unroll
    for (int i = 0; i < 4; ++i) {
      const int idx = i * 256 + tid;
      const int row = idx >> 3;
      const int c   = (idx & 7) << 3;
      i32x4 v = *(const i32x4*)(P + (size_t)(n0 + row) * PKW + ((kt + c) >> 1));
      s16x8 o;
#pragma unroll
      for (int j = 0; j < 4; ++j) {
        const int b = v[j];
        o[2 * j]     = (short)f2bf((float)((b & 15) - 7));
        o[2 * j + 1] = (short)f2bf((float)(((b >> 4) & 15) - 7));
      }
      *(s16x8*)(Bs + row * BK + (c ^ ((row & 7) << 3))) = o;
    }
    __syncthreads();
#pragma unroll
    for (int kk = 0; kk < 2; ++kk) {
      const int rsel = lane & 15;
      const int ksel = ((((lane >> 4) << 3) + kk * 32)) ^ ((lane & 7) << 3);
      s16x8 af[4], bfr[4];
#pragma unroll
      for (int m = 0; m < 4; ++m)
        af[m] = *(const s16x8*)(As + (wr + m * 16 + rsel) * BK + ksel);
#pragma unroll
      for (int n = 0; n < 4; ++n)
        bfr[n] = *(const s16x8*)(Bs + (wc + n * 16 + rsel) * BK + ksel);
#pragma unroll
      for (int m = 0; m < 4; ++m)
#pragma unroll
        for (int n = 0; n < 4; ++n)
          acc[m][n] = __builtin_amdgcn_mfma_f32_16x16x32_bf16(af[m], bfr[n], acc[m][n], 0, 0, 0);
    }
    __syncthreads();
  }

  const int crow = wr + ((lane >> 4) << 2);
  const int ccol = wc + (lane & 15);
#pragma unroll
  for (int n = 0; n < 4; ++n) {
    const int gc = n0 + ccol + n * 16;
    const float sc = scale[gc];
    const float bi = bias[gc];
#pragma unroll
    for (int m = 0; m < 4; ++m) {
      float* cp = C + (size_t)(m0 + crow + m * 16) * NN + gc;
#pragma unroll
      for (int r = 0; r < 4; ++r)
        cp[(size_t)r * NN] = acc[m][n][r] * sc + bi;
    }
  }
}

// ---------------- launch ----------------

extern "C" void kernel_launch(void* const* d_in, const int* in_sizes, int n_in,
                              void* d_out, int out_size, void* d_ws, size_t ws_size,
                              hipStream_t stream) {
  const float* x      = (const float*)d_in[0];
  const int*   packed = (const int*)d_in[1];
  const float* scale  = (const float*)d_in[2];
  const float* bias   = (const float*)d_in[3];
  float* y = (float*)d_out;

  const size_t nA = (size_t)MM * KK * sizeof(unsigned short);   // 64 MiB
  const size_t nB = (size_t)NN * KK * sizeof(unsigned short);   // ~86 MiB

  if (ws_size >= nA + nB) {
    unsigned short* xb = (unsigned short*)d_ws;
    unsigned short* wb = (unsigned short*)((char*)d_ws + nA);
    int4lin_cvt_x<<<2048, 256, 0, stream>>>(x, xb);
    int4lin_deq_w<<<2048, 256, 0, stream>>>(packed, wb);
    int4lin_gemm_8p<<<(NN / BN) * (MM / BM), 512, 0, stream>>>(xb, wb, scale, bias, y);
  } else {
    dim3 grid(NN / 128, MM / 128);
    int4lin_gemm_inline<<<grid, 256, 0, stream>>>(x, packed, scale, bias, y);
  }
}

// Round 6
// 921.525 us; speedup vs baseline: 1.3250x; 1.0173x over previous
//
#include <hip/hip_runtime.h>
#include <hip/hip_bf16.h>

#define MM 8192
#define NN 11008
#define KK 4096
#define PKW 2048   // packed int32 words per output row

#define BM 256
#define BN 256
#define BK 64
#define NT (KK / BK)   // 64 K-tiles

typedef __attribute__((ext_vector_type(4))) float f32x4;
typedef __attribute__((ext_vector_type(4))) int   i32x4;
typedef __attribute__((ext_vector_type(8))) short s16x8;
typedef __attribute__((ext_vector_type(4))) short s16x4;

typedef __attribute__((address_space(3))) unsigned char        lds_u8;
typedef const __attribute__((address_space(1))) unsigned char  glb_u8;

static __device__ __forceinline__ unsigned short f2bf(float f) {
  union { float f; unsigned int u; } v; v.f = f;
  unsigned int u = v.u;
  u += 0x7fffu + ((u >> 16) & 1u);   // RNE
  return (unsigned short)(u >> 16);
}

// ---------------- preprocessing (writes PRE-SWIZZLED: 16B group g -> g ^ (row&7)
// within each 64-element block; GEMM stages linearly via global_load_lds and
// applies the same XOR on ds_read — rule #21 both-sides) ----------------

__global__ void int4lin_cvt_x(const float* __restrict__ X, unsigned short* __restrict__ O) {
  const int n8 = (MM * KK) / 8;
  int i = blockIdx.x * blockDim.x + threadIdx.x;
  const int stride = gridDim.x * blockDim.x;
  for (; i < n8; i += stride) {
    const int row = i >> 9;            // KK/8 = 512 groups per row
    const int g   = i & 511;
    const int gs  = (g & ~7) | ((g & 7) ^ (row & 7));   // swizzled group
    const f32x4* p = (const f32x4*)(X + (size_t)i * 8);
    f32x4 a = p[0];
    f32x4 b = p[1];
    s16x8 o;
    o[0] = (short)f2bf(a[0]); o[1] = (short)f2bf(a[1]);
    o[2] = (short)f2bf(a[2]); o[3] = (short)f2bf(a[3]);
    o[4] = (short)f2bf(b[0]); o[5] = (short)f2bf(b[1]);
    o[6] = (short)f2bf(b[2]); o[7] = (short)f2bf(b[3]);
    *(s16x8*)(O + (size_t)row * KK + (size_t)gs * 8) = o;
  }
}

__global__ void int4lin_deq_w(const int* __restrict__ P, unsigned short* __restrict__ O) {
  const int n4 = (NN * PKW) / 4;     // each i: 4 words -> one 8-elem bf16 group
  int i = blockIdx.x * blockDim.x + threadIdx.x;
  const int stride = gridDim.x * blockDim.x;
  for (; i < n4; i += stride) {
    const int row = i >> 9;            // 512 groups per row
    const int g   = i & 511;
    const int gs  = (g & ~7) | ((g & 7) ^ (row & 7));
    i32x4 v = *(const i32x4*)(P + (size_t)i * 4);
    s16x8 o;
#pragma unroll
    for (int j = 0; j < 4; ++j) {
      int b = v[j];
      o[2 * j]     = (short)f2bf((float)((b & 15) - 7));
      o[2 * j + 1] = (short)f2bf((float)(((b >> 4) & 15) - 7));
    }
    *(s16x8*)(O + (size_t)row * KK + (size_t)gs * 8) = o;
  }
}

// ---------------- 256x256 GEMM, free-running 2-sync tile loop ----------------
//
// Staging ring (8 gloads/tile): SP1: A(t+1) late q1,q3 | SP3: B(t+2) q0-3 |
// SP4: A(t+2) early q0,q2. Boundary wait vmcnt(6) leaves exactly tile-(t+1)'s
// 6 loads in flight. Only 2 barriers/tile:
//   S1 (after SP2): all waves' B + A-early reads complete -> safe to stage
//      B(t+2)/A-early(t+2) into the live buffer (SP3/SP4).
//   S2 (tile boundary): vmcnt(6) + barrier -> tile t+1 fully staged.
// A-late reads (rows q1,q3) vs A-early stores (rows q0,q2) are disjoint.
// No lockstep phases: waves drift; LDS pipe and MFMA pipe overlap across waves.

__global__ __launch_bounds__(512, 2) void int4lin_gemm_fr(
    const unsigned short* __restrict__ Aw,   // M x K bf16, group-swizzled
    const unsigned short* __restrict__ Bw,   // N x K bf16 (q values), group-swizzled
    const float* __restrict__ scale,
    const float* __restrict__ bias,
    float* __restrict__ C)
{
  __shared__ unsigned short As[2][BM * BK];   // 2 x 32 KiB
  __shared__ unsigned short Bs[2][BN * BK];   // 2 x 32 KiB  -> 128 KiB total

  const int tid  = threadIdx.x;
  const int lane = tid & 63;
  const int wave = tid >> 6;
  const int wm = wave >> 2;          // 0..1
  const int wn = wave & 3;           // 0..3

  // T1: bijective XCD swizzle (1376 = 8*172); consecutive swz share bm (A-panel in L2)
  const int bid = blockIdx.x;
  const int swz = (bid & 7) * 172 + (bid >> 3);
  const int bm = swz / 43;
  const int bn = swz - bm * 43;
  const size_t m0 = (size_t)bm * BM;
  const size_t n0 = (size_t)bn * BN;

  const int rsel = lane & 15;
  const int gq   = lane >> 4;        // k-slot base (0..3); kk1 slot = gq+4
  const int rx7  = lane & 7;         // T2 swizzle key (== row&7 of fragment rows)

  f32x4 acc[8][4] = {};

  const int arow = wm * 128 + rsel;  // + m*16
  const int brow = wn * 64  + rsel;  // + n*16

  // LDS fragment read with T2 XOR on the 16B slot index
#define LDF(base, row, slot) \
  (*(const s16x8*)((const char*)(base) + (size_t)((row) * 128 + (((slot) ^ rx7) << 4))))

  const int srow = tid >> 3;          // 0..63
  const int scol = (tid & 7) << 3;    // bf16 col, x8

  // one 64x64 quarter = 8 KiB = 1 global_load_lds per thread
  auto stage_a_q = [&](int buf, int kt, int q) {
    __builtin_amdgcn_global_load_lds(
        (glb_u8*)(Aw + (m0 + q * 64 + srow) * KK + kt + scol),
        (lds_u8*)((char*)&As[buf][0] + q * 8192 + tid * 16), 16, 0, 0);
  };
  auto stage_b_q = [&](int buf, int kt, int q) {
    __builtin_amdgcn_global_load_lds(
        (glb_u8*)(Bw + (n0 + q * 64 + srow) * KK + kt + scol),
        (lds_u8*)((char*)&Bs[buf][0] + q * 8192 + tid * 16), 16, 0, 0);
  };

  // -------- prologue: tile0 fully (8), tile1 partially (6); vmcnt(6) --------
#pragma unroll
  for (int q = 0; q < 4; ++q) stage_b_q(0, 0, q);
  stage_a_q(0, 0, 0); stage_a_q(0, 0, 2);
  stage_a_q(0, 0, 1); stage_a_q(0, 0, 3);
#pragma unroll
  for (int q = 0; q < 4; ++q) stage_b_q(1, BK, q);
  stage_a_q(1, BK, 0); stage_a_q(1, BK, 2);
  asm volatile("s_waitcnt vmcnt(6)\n\ts_barrier" ::: "memory");

#pragma unroll 1
  for (int t = 0; t < NT; ++t) {
    const int rbuf = t & 1;
    const unsigned short* Ab = &As[rbuf][0];
    const unsigned short* Bb = &Bs[rbuf][0];
    s16x8 a0[4], a1[4], b0[4], b1[4];

    // ---- SP1: stage A(t+1) late; read a[m0-3]kk0 + b[all]kk0; MFMA
    if (t + 1 < NT) {
      stage_a_q(rbuf ^ 1, (t + 1) * BK, 1);
      stage_a_q(rbuf ^ 1, (t + 1) * BK, 3);
    }
#pragma unroll
    for (int m = 0; m < 4; ++m) a0[m] = LDF(Ab, arow + m * 16, gq);
#pragma unroll
    for (int n = 0; n < 4; ++n) b0[n] = LDF(Bb, brow + n * 16, gq);
    __builtin_amdgcn_s_setprio(1);
#pragma unroll
    for (int m = 0; m < 4; ++m)
#pragma unroll
      for (int n = 0; n < 4; ++n)
        acc[m][n] = __builtin_amdgcn_mfma_f32_16x16x32_bf16(a0[m], b0[n], acc[m][n], 0, 0, 0);
    __builtin_amdgcn_s_setprio(0);

    // ---- SP2: read a[m0-3]kk1 + b[all]kk1; MFMA
#pragma unroll
    for (int m = 0; m < 4; ++m) a1[m] = LDF(Ab, arow + m * 16, gq + 4);
#pragma unroll
    for (int n = 0; n < 4; ++n) b1[n] = LDF(Bb, brow + n * 16, gq + 4);
    __builtin_amdgcn_s_setprio(1);
#pragma unroll
    for (int m = 0; m < 4; ++m)
#pragma unroll
      for (int n = 0; n < 4; ++n)
        acc[m][n] = __builtin_amdgcn_mfma_f32_16x16x32_bf16(a1[m], b1[n], acc[m][n], 0, 0, 0);
    __builtin_amdgcn_s_setprio(0);

    // ---- S1: all waves' B + A-early reads of this tile are complete
    asm volatile("s_barrier" ::: "memory");

    // ---- SP3: stage B(t+2); read a[m4-7]kk0; MFMA (b0 live in regs)
    if (t + 2 < NT) {
#pragma unroll
      for (int q = 0; q < 4; ++q) stage_b_q(rbuf, (t + 2) * BK, q);
    }
#pragma unroll
    for (int m = 0; m < 4; ++m) a0[m] = LDF(Ab, arow + (m + 4) * 16, gq);
    __builtin_amdgcn_s_setprio(1);
#pragma unroll
    for (int m = 0; m < 4; ++m)
#pragma unroll
      for (int n = 0; n < 4; ++n)
        acc[m + 4][n] = __builtin_amdgcn_mfma_f32_16x16x32_bf16(a0[m], b0[n], acc[m + 4][n], 0, 0, 0);
    __builtin_amdgcn_s_setprio(0);

    // ---- SP4: stage A(t+2) early; read a[m4-7]kk1; MFMA
    if (t + 2 < NT) {
      stage_a_q(rbuf, (t + 2) * BK, 0);
      stage_a_q(rbuf, (t + 2) * BK, 2);
    }
#pragma unroll
    for (int m = 0; m < 4; ++m) a1[m] = LDF(Ab, arow + (m + 4) * 16, gq + 4);
    __builtin_amdgcn_s_setprio(1);
#pragma unroll
    for (int m = 0; m < 4; ++m)
#pragma unroll
      for (int n = 0; n < 4; ++n)
        acc[m + 4][n] = __builtin_amdgcn_mfma_f32_16x16x32_bf16(a1[m], b1[n], acc[m + 4][n], 0, 0, 0);
    __builtin_amdgcn_s_setprio(0);

    // ---- S2: tile boundary — counted wait keeps 6 loads in flight
    if (t < NT - 2)       asm volatile("s_waitcnt vmcnt(6)\n\ts_barrier" ::: "memory");
    else if (t == NT - 2) asm volatile("s_waitcnt vmcnt(0)\n\ts_barrier" ::: "memory");
    else                  asm volatile("s_barrier" ::: "memory");
  }

  // epilogue: y = acc * scale[col] + bias[col]; C/D map col=lane&15, row=gq*4+r
  const size_t crow0 = m0 + wm * 128 + (gq << 2);
  const size_t ccol0 = n0 + wn * 64 + rsel;
#pragma unroll
  for (int n = 0; n < 4; ++n) {
    const size_t gc = ccol0 + n * 16;
    const float sc = scale[gc];
    const float bi = bias[gc];
#pragma unroll
    for (int m = 0; m < 8; ++m) {
      float* cp = C + (crow0 + m * 16) * NN + gc;
#pragma unroll
      for (int r = 0; r < 4; ++r)
        cp[(size_t)r * NN] = acc[m][n][r] * sc + bi;
    }
  }
#undef LDF
}

// ---------------- GEMM, inline-conversion fallback (no workspace needed) ----------------

__global__ __launch_bounds__(256) void int4lin_gemm_inline(
    const float* __restrict__ X,
    const int* __restrict__ P,
    const float* __restrict__ scale,
    const float* __restrict__ bias,
    float* __restrict__ C)
{
  __shared__ unsigned short As[128 * BK];
  __shared__ unsigned short Bs[128 * BK];

  const int tid  = threadIdx.x;
  const int lane = tid & 63;
  const int wave = tid >> 6;
  const int m0 = blockIdx.y * 128;
  const int n0 = blockIdx.x * 128;
  const int wr = (wave >> 1) * 64;
  const int wc = (wave & 1) * 64;

  f32x4 acc[4][4] = {};

  for (int kt = 0; kt < KK; kt += BK) {
#pragma unroll
    for (int i = 0; i < 8; ++i) {
      const int idx = i * 256 + tid;
      const int row = idx >> 4;
      const int c   = (idx & 15) << 2;
      f32x4 v = *(const f32x4*)(X + (size_t)(m0 + row) * KK + kt + c);
      s16x4 o;
      o[0] = (short)f2bf(v[0]); o[1] = (short)f2bf(v[1]);
      o[2] = (short)f2bf(v[2]); o[3] = (short)f2bf(v[3]);
      *(s16x4*)(As + row * BK + (c ^ ((row & 7) << 3))) = o;
    }
#pragma unroll
    for (int i = 0; i < 4; ++i) {
      const int idx = i * 256 + tid;
      const int row = idx >> 3;
      const int c   = (idx & 7) << 3;
      i32x4 v = *(const i32x4*)(P + (size_t)(n0 + row) * PKW + ((kt + c) >> 1));
      s16x8 o;
#pragma unroll
      for (int j = 0; j < 4; ++j) {
        const int b = v[j];
        o[2 * j]     = (short)f2bf((float)((b & 15) - 7));
        o[2 * j + 1] = (short)f2bf((float)(((b >> 4) & 15) - 7));
      }
      *(s16x8*)(Bs + row * BK + (c ^ ((row & 7) << 3))) = o;
    }
    __syncthreads();
#pragma unroll
    for (int kk = 0; kk < 2; ++kk) {
      const int rsel = lane & 15;
      const int ksel = ((((lane >> 4) << 3) + kk * 32)) ^ ((lane & 7) << 3);
      s16x8 af[4], bfr[4];
#pragma unroll
      for (int m = 0; m < 4; ++m)
        af[m] = *(const s16x8*)(As + (wr + m * 16 + rsel) * BK + ksel);
#pragma unroll
      for (int n = 0; n < 4; ++n)
        bfr[n] = *(const s16x8*)(Bs + (wc + n * 16 + rsel) * BK + ksel);
#pragma unroll
      for (int m = 0; m < 4; ++m)
#pragma unroll
        for (int n = 0; n < 4; ++n)
          acc[m][n] = __builtin_amdgcn_mfma_f32_16x16x32_bf16(af[m], bfr[n], acc[m][n], 0, 0, 0);
    }
    __syncthreads();
  }

  const int crow = wr + ((lane >> 4) << 2);
  const int ccol = wc + (lane & 15);
#pragma unroll
  for (int n = 0; n < 4; ++n) {
    const int gc = n0 + ccol + n * 16;
    const float sc = scale[gc];
    const float bi = bias[gc];
#pragma unroll
    for (int m = 0; m < 4; ++m) {
      float* cp = C + (size_t)(m0 + crow + m * 16) * NN + gc;
#pragma unroll
      for (int r = 0; r < 4; ++r)
        cp[(size_t)r * NN] = acc[m][n][r] * sc + bi;
    }
  }
}

// ---------------- launch ----------------

extern "C" void kernel_launch(void* const* d_in, const int* in_sizes, int n_in,
                              void* d_out, int out_size, void* d_ws, size_t ws_size,
                              hipStream_t stream) {
  const float* x      = (const float*)d_in[0];
  const int*   packed = (const int*)d_in[1];
  const float* scale  = (const float*)d_in[2];
  const float* bias   = (const float*)d_in[3];
  float* y = (float*)d_out;

  const size_t nA = (size_t)MM * KK * sizeof(unsigned short);   // 64 MiB
  const size_t nB = (size_t)NN * KK * sizeof(unsigned short);   // ~86 MiB

  if (ws_size >= nA + nB) {
    unsigned short* xb = (unsigned short*)d_ws;
    unsigned short* wb = (unsigned short*)((char*)d_ws + nA);
    int4lin_cvt_x<<<2048, 256, 0, stream>>>(x, xb);
    int4lin_deq_w<<<2048, 256, 0, stream>>>(packed, wb);
    int4lin_gemm_fr<<<(NN / BN) * (MM / BM), 512, 0, stream>>>(xb, wb, scale, bias, y);
  } else {
    dim3 grid(NN / 128, MM / 128);
    int4lin_gemm_inline<<<grid, 256, 0, stream>>>(x, packed, scale, bias, y);
  }
}